// Round 8
// baseline (568.581 us; speedup 1.0000x reference)
//
#include <hip/hip_runtime.h>
#include <hip/hip_bf16.h>
#include <math.h>

#define Bsz 16384
#define HIDc 1024

typedef __attribute__((ext_vector_type(8))) short short8_t;
typedef __attribute__((ext_vector_type(4))) float f32x4;
typedef __attribute__((ext_vector_type(4))) short s16x4;

typedef __attribute__((address_space(1))) const unsigned char* gp1_t;
typedef __attribute__((address_space(3))) unsigned char* lp3_t;

__device__ __forceinline__ float sigf(float x) { return 1.0f / (1.0f + __expf(-x)); }
__device__ __forceinline__ float tanh_fast(float x) {
  x = fminf(fmaxf(x, -10.f), 10.f);
  float t = __expf(2.f * x);
  return (t - 1.f) / (t + 1.f);
}

// Bijective XCD-chunked swizzle (T1). r2 evidence: FETCH 573->280 MB.
__device__ __forceinline__ int xcd_map(int bid, int nwg) {
  const int q = nwg >> 3, r = nwg & 7;
  const int xcd = bid & 7, idx = bid >> 3;
  return (xcd < r ? xcd * (q + 1) : r * (q + 1) + (xcd - r) * q) + idx;
}

// inline-asm ds_read_b128: keeps compiler alias analysis from inserting
// conservative waits against in-flight global_load_lds (r5's failure).
#define DSR(dst, addr, IMM) \
  asm volatile("ds_read_b128 %0, %1 offset:" IMM : "=v"(dst) : "v"(addr))

// Stage one 256x64 A half + 256x64 B half (64 KB): 8 x 16B loads/thread.
// LDS dest linear; XOR slot swizzle pre-applied on the GLOBAL source col
// (rule #21) — the r4/r6/r7-proven conflict-free layout.
#define STAGE_ADV(BUFB) do {                                                                     \
    __hip_bfloat16* db_ = lds + (BUFB);                                                          \
    __builtin_amdgcn_global_load_lds((gp1_t)pa0, (lp3_t)(db_ + tid * 8), 16, 0, 0);              \
    __builtin_amdgcn_global_load_lds((gp1_t)pa1, (lp3_t)(db_ + (512 + tid) * 8), 16, 0, 0);      \
    __builtin_amdgcn_global_load_lds((gp1_t)pa2, (lp3_t)(db_ + (1024 + tid) * 8), 16, 0, 0);     \
    __builtin_amdgcn_global_load_lds((gp1_t)pa3, (lp3_t)(db_ + (1536 + tid) * 8), 16, 0, 0);     \
    __builtin_amdgcn_global_load_lds((gp1_t)pb0, (lp3_t)(db_ + 16384 + tid * 8), 16, 0, 0);      \
    __builtin_amdgcn_global_load_lds((gp1_t)pb1, (lp3_t)(db_ + 16384 + (512 + tid) * 8), 16, 0, 0); \
    __builtin_amdgcn_global_load_lds((gp1_t)pb2, (lp3_t)(db_ + 16384 + (1024 + tid) * 8), 16, 0, 0); \
    __builtin_amdgcn_global_load_lds((gp1_t)pb3, (lp3_t)(db_ + 16384 + (1536 + tid) * 8), 16, 0, 0); \
    pa0 += 64; pa1 += 64; pa2 += 64; pa3 += 64;                                                  \
    pb0 += 64; pb1 += 64; pb2 += 64; pb3 += 64;                                                  \
  } while (0)

// One quadrant's MFMA cluster: wait own ds_reads, pin below (rule #18), 16 MFMA.
#define MFMA_Q(QM, QN) do {                                                      \
    asm volatile("s_waitcnt lgkmcnt(0)" ::: "memory");                           \
    __builtin_amdgcn_sched_barrier(0);                                           \
    __builtin_amdgcn_s_setprio(1);                                               \
    _Pragma("unroll") for (int ks = 0; ks < 2; ++ks)                             \
      _Pragma("unroll") for (int mf = 0; mf < 4; ++mf)                           \
        _Pragma("unroll") for (int nf = 0; nf < 2; ++nf)                         \
          acc[(QM) * 4 + mf][(QN) * 2 + nf] =                                    \
              __builtin_amdgcn_mfma_f32_16x16x32_bf16(                           \
                  a8[mf][ks], b8[QN][nf][ks],                                    \
                  acc[(QM) * 4 + mf][(QN) * 2 + nf], 0, 0, 0);                   \
    __builtin_amdgcn_s_setprio(0);                                               \
    __builtin_amdgcn_sched_barrier(0);                                           \
  } while (0)

// 256x256 tile, BK=64, 8 waves (2M x 4N), per-wave 128x64 out. Two 64 KB LDS
// buffers; m201 4-quadrant phase schedule per K-tile: each phase = {ds_reads,
// barrier, lgkmcnt(0), 16 MFMA, barrier}; staging burst + counted vmcnt(8)
// only in phase q3 (never drains the pipeline mid-loop).
// EPI 0: G1 — col<1024: rs=sig(v+br)*state; else u=sig(v+bu)
// EPI 1: G2 — col<1024: sem=relu(v+b1)->SN(ld2048); else cx=v+bc->out1
// EPI 2: G3 — nei=relu(v+b2)->out0+1024 (ld2048)
// EPI 3: final_c — cb=tanh(v+auxbf)->out0
// EPI 4: final_g — outf=u*st+(1-u)*cb*sig(v+bg)
template <int EPI>
__global__ __launch_bounds__(512, 2)
void gemm256(const __hip_bfloat16* __restrict__ A, long lda,
             const __hip_bfloat16* __restrict__ Wt, long ldw, int nbx,
             const float* __restrict__ bias0, const float* __restrict__ bias1,
             const __hip_bfloat16* __restrict__ stbf,   // A1 (state at col 1024+)
             const __hip_bfloat16* __restrict__ auxbf,  // EPI3: CXb
             const __hip_bfloat16* __restrict__ CB,     // EPI4
             const __hip_bfloat16* __restrict__ U,      // EPI4
             __hip_bfloat16* __restrict__ out0,
             __hip_bfloat16* __restrict__ out1,
             float* __restrict__ outf) {
  constexpr int KC = (EPI == 0 || EPI == 4) ? 2048 : 1024;
  constexpr int NS = KC / 64;
  __shared__ __hip_bfloat16 lds[2 * 32768];   // 128 KB: 2 x (A 32KB + B 32KB)

  const int tid = threadIdx.x;
  const int wave = tid >> 6, lane = tid & 63;
  const int wr = wave >> 2, wc = wave & 3;
  const int lm = lane & 15, hi = lane >> 4, l7 = lane & 7;

  const int wg = xcd_map(blockIdx.x, gridDim.x);
  const long mBase = (long)(wg / nbx) * 256;
  const long nBase = (long)(wg % nbx) * 256;
  const __hip_bfloat16* Ablk = A + mBase * lda;
  const __hip_bfloat16* Wblk = Wt + nBase * ldw;

  // Pre-swizzled global staging pointers (advance 64 cols per staged K-tile).
  const __hip_bfloat16 *pa0, *pa1, *pa2, *pa3, *pb0, *pb1, *pb2, *pb3;
  {
    const int s0 = tid, s1 = 512 + tid, s2 = 1024 + tid, s3 = 1536 + tid;
    const int r0 = s0 >> 3, r1 = s1 >> 3, r2 = s2 >> 3, r3 = s3 >> 3;
    const int c0 = ((s0 & 7) ^ (r0 & 7)) << 3, c1 = ((s1 & 7) ^ (r1 & 7)) << 3;
    const int c2 = ((s2 & 7) ^ (r2 & 7)) << 3, c3 = ((s3 & 7) ^ (r3 & 7)) << 3;
    pa0 = Ablk + (long)r0 * lda + c0;  pa1 = Ablk + (long)r1 * lda + c1;
    pa2 = Ablk + (long)r2 * lda + c2;  pa3 = Ablk + (long)r3 * lda + c3;
    pb0 = Wblk + (long)r0 * ldw + c0;  pb1 = Wblk + (long)r1 * ldw + c1;
    pb2 = Wblk + (long)r2 * ldw + c2;  pb3 = Wblk + (long)r3 * ldw + c3;
  }

  const unsigned ldsbase = (unsigned)(size_t)(void*)lds;
  const unsigned laneA = (unsigned)((wr * 128 + lm) * 128 + ((hi ^ l7) << 4));
  const unsigned laneB = (unsigned)(32768 + (wc * 64 + lm) * 128 + ((hi ^ l7) << 4));

  f32x4 acc[8][4];
#pragma unroll
  for (int m = 0; m < 8; ++m)
#pragma unroll
    for (int n = 0; n < 4; ++n) acc[m][n] = (f32x4){0.f, 0.f, 0.f, 0.f};

  // a8: current qm's 4 m-frags x 2 ks; b8: BOTH qn's frags stay live.
  short8_t a8[4][2], b8[2][2][2];

  STAGE_ADV(0);        // K-tile 0 -> buf0
  STAGE_ADV(32768);    // K-tile 1 -> buf1
  asm volatile("s_waitcnt vmcnt(8)" ::: "memory");   // tile 0 landed
  __builtin_amdgcn_s_barrier();

#pragma unroll 1
  for (int s = 0; s < NS; ++s) {
    const unsigned base = ldsbase + (unsigned)((s & 1) * 65536);
    const unsigned a0 = base + laneA, b0 = base + laneB;
    const unsigned a1 = a0 ^ 64u, b1 = b0 ^ 64u;   // k-half toggle (slot bit2)

    // ---- q0: quadrant (0,0) — reads A0 (8) + B0 (4) ----
    DSR(a8[0][0], a0, "0"); DSR(a8[1][0], a0, "2048");
    DSR(a8[2][0], a0, "4096"); DSR(a8[3][0], a0, "6144");
    DSR(a8[0][1], a1, "0"); DSR(a8[1][1], a1, "2048");
    DSR(a8[2][1], a1, "4096"); DSR(a8[3][1], a1, "6144");
    DSR(b8[0][0][0], b0, "0"); DSR(b8[0][1][0], b0, "2048");
    DSR(b8[0][0][1], b1, "0"); DSR(b8[0][1][1], b1, "2048");
    __builtin_amdgcn_s_barrier();
    MFMA_Q(0, 0);
    __builtin_amdgcn_s_barrier();

    // ---- q1: quadrant (0,1) — reads B1 (4) ----
    DSR(b8[1][0][0], b0, "4096"); DSR(b8[1][1][0], b0, "6144");
    DSR(b8[1][0][1], b1, "4096"); DSR(b8[1][1][1], b1, "6144");
    __builtin_amdgcn_s_barrier();
    MFMA_Q(0, 1);
    __builtin_amdgcn_s_barrier();

    // ---- q2: quadrant (1,0) — reads A1 (8) ----
    DSR(a8[0][0], a0, "8192"); DSR(a8[1][0], a0, "10240");
    DSR(a8[2][0], a0, "12288"); DSR(a8[3][0], a0, "14336");
    DSR(a8[0][1], a1, "8192"); DSR(a8[1][1], a1, "10240");
    DSR(a8[2][1], a1, "12288"); DSR(a8[3][1], a1, "14336");
    __builtin_amdgcn_s_barrier();
    MFMA_Q(1, 0);
    __builtin_amdgcn_s_barrier();

    // ---- q3: quadrant (1,1) — no reads; restage + counted vmcnt ----
    if (s + 2 < NS) STAGE_ADV((s & 1) * 32768);    // buf cur, for tile s+2
    __builtin_amdgcn_s_barrier();
    MFMA_Q(1, 1);
    // retire tile s+1's 8 loads (s+2's stay in flight); drain only at the end
    if (s + 2 < NS) asm volatile("s_waitcnt vmcnt(8)" ::: "memory");
    else            asm volatile("s_waitcnt vmcnt(0)" ::: "memory");
    __builtin_amdgcn_s_barrier();
  }

  // Epilogue: wave writes 128x64 at (mBase + wr*128, nBase + wc*64).
#pragma unroll
  for (int mf = 0; mf < 8; ++mf)
#pragma unroll
    for (int nf = 0; nf < 4; ++nf)
#pragma unroll
      for (int j = 0; j < 4; ++j) {
        const long row = mBase + wr * 128 + mf * 16 + hi * 4 + j;
        const int col = (int)nBase + wc * 64 + nf * 16 + lm;
        const float v = acc[mf][nf][j];
        if (EPI == 0) {
          if (col < HIDc) {
            float rr = sigf(v + bias0[col]);
            float st = __bfloat162float(stbf[row * 2048 + 1024 + col]);
            out0[row * HIDc + col] = __float2bfloat16(rr * st);
          } else {
            int c = col - HIDc;
            out1[row * HIDc + c] = __float2bfloat16(sigf(v + bias1[c]));
          }
        } else if (EPI == 1) {
          if (col < HIDc) {
            out0[row * 2048 + col] = __float2bfloat16(fmaxf(v + bias0[col], 0.f));
          } else {
            int c = col - HIDc;
            out1[row * HIDc + c] = __float2bfloat16(v + bias1[c]);
          }
        } else if (EPI == 2) {
          out0[row * 2048 + HIDc + col] = __float2bfloat16(fmaxf(v + bias0[col], 0.f));
        } else if (EPI == 3) {
          const long idx = row * HIDc + col;
          out0[idx] = __float2bfloat16(tanh_fast(v + __bfloat162float(auxbf[idx])));
        } else {
          const long idx = row * HIDc + col;
          float g = sigf(v + bias0[col]);
          float u = __bfloat162float(U[idx]);
          float cb = __bfloat162float(CB[idx]);
          float st = __bfloat162float(stbf[row * 2048 + 1024 + col]);
          outf[idx] = u * st + (1.f - u) * cb * g;
        }
      }
}

// One prep kernel: blocks [0,10240) transpose all 7 weight views to (N,K)
// bf16; blocks [10240,12288) pack activations to bf16 (A1=[x|state], NB).
__global__ __launch_bounds__(256)
void prep_k(const float4* __restrict__ in4, const float4* __restrict__ st4,
            __hip_bfloat16* __restrict__ A1, __hip_bfloat16* __restrict__ NB,
            const float* __restrict__ Wr, const float* __restrict__ Wu,
            const float* __restrict__ W1, const float* __restrict__ Wc,
            const float* __restrict__ W2, const float* __restrict__ Wg,
            __hip_bfloat16* __restrict__ Wru_t, __hip_bfloat16* __restrict__ W1cx_t,
            __hip_bfloat16* __restrict__ Wcb_t, __hip_bfloat16* __restrict__ W2_t,
            __hip_bfloat16* __restrict__ Wg_t) {
  const int bid = blockIdx.x;
  if (bid < 10240) {
    const float* s_; __hip_bfloat16* d_; long ldo; int j, ktiles;
    if (bid < 2048)      { j = bid;        s_ = Wr; d_ = Wru_t;               ldo = 2048; ktiles = 64; }
    else if (bid < 4096) { j = bid - 2048; s_ = Wu; d_ = Wru_t + 1024L * 2048; ldo = 2048; ktiles = 64; }
    else if (bid < 5120) { j = bid - 4096; s_ = W1; d_ = W1cx_t;              ldo = 1024; ktiles = 32; }
    else if (bid < 6144) { j = bid - 5120; s_ = Wc; d_ = W1cx_t + 1024L * 1024; ldo = 1024; ktiles = 32; }
    else if (bid < 7168) { j = bid - 6144; s_ = Wc + 1024L * 1024; d_ = Wcb_t; ldo = 1024; ktiles = 32; }
    else if (bid < 8192) { j = bid - 7168; s_ = W2; d_ = W2_t;                ldo = 1024; ktiles = 32; }
    else                 { j = bid - 8192; s_ = Wg; d_ = Wg_t;                ldo = 2048; ktiles = 64; }
    const int k0 = (j % ktiles) * 32, n0 = (j / ktiles) * 32;
    __shared__ float t[32][33];
    const int tx = threadIdx.x & 31, ty = threadIdx.x >> 5;
#pragma unroll
    for (int dy = 0; dy < 32; dy += 8)
      t[ty + dy][tx] = s_[(long)(k0 + ty + dy) * 1024 + n0 + tx];
    __syncthreads();
#pragma unroll
    for (int dy = 0; dy < 32; dy += 8)
      d_[(long)(n0 + ty + dy) * ldo + k0 + tx] = __float2bfloat16(t[tx][ty + dy]);
  } else {
    const long NI4 = (long)Bsz * 2048 / 4;
    const long NS4 = (long)Bsz * 1024 / 4;
    for (long i = (long)(bid - 10240) * 256 + threadIdx.x; i < NI4 + NS4;
         i += 2048L * 256) {
      float4 v;
      __hip_bfloat16* dst;
      if (i < NI4) {
        v = in4[i];
        long e = i << 2;
        long row = e >> 11;
        int col = (int)(e & 2047);
        dst = (col < 1024) ? (A1 + row * 2048 + col) : (NB + row * 1024 + (col - 1024));
      } else {
        long jj = i - NI4;
        v = st4[jj];
        long e = jj << 2;
        long row = e >> 10;
        int col = (int)(e & 1023);
        dst = A1 + row * 2048 + 1024 + col;
      }
      union { __hip_bfloat16 h[4]; s16x4 s; } u;
      u.h[0] = __float2bfloat16(v.x);
      u.h[1] = __float2bfloat16(v.y);
      u.h[2] = __float2bfloat16(v.z);
      u.h[3] = __float2bfloat16(v.w);
      *reinterpret_cast<s16x4*>(dst) = u.s;
    }
  }
}

extern "C" void kernel_launch(void* const* d_in, const int* in_sizes, int n_in,
                              void* d_out, int out_size, void* d_ws, size_t ws_size,
                              hipStream_t stream) {
  const float* inputs = (const float*)d_in[0];
  const float* state = (const float*)d_in[1];
  const float* Wr = (const float*)d_in[2];
  const float* br = (const float*)d_in[3];
  const float* Wu = (const float*)d_in[4];
  const float* bu = (const float*)d_in[5];
  const float* Wc = (const float*)d_in[6];
  const float* bc = (const float*)d_in[7];
  const float* W1 = (const float*)d_in[8];
  const float* b1 = (const float*)d_in[9];
  const float* W2 = (const float*)d_in[10];
  const float* b2 = (const float*)d_in[11];
  const float* Wg = (const float*)d_in[12];
  const float* bg = (const float*)d_in[13];
  float* out = (float*)d_out;

  char* ws = (char*)d_ws;
  __hip_bfloat16* A1    = (__hip_bfloat16*)(ws);                 // 64 MB [x|state]
  __hip_bfloat16* NB    = (__hip_bfloat16*)(ws + 67108864L);     // 32 MB neighbors -> CB
  __hip_bfloat16* RS    = (__hip_bfloat16*)(ws + 100663296L);    // 32 MB r*state
  __hip_bfloat16* Ub    = (__hip_bfloat16*)(ws + 134217728L);    // 32 MB u
  __hip_bfloat16* SN    = (__hip_bfloat16*)(ws + 167772160L);    // 64 MB [sem|nei]
  __hip_bfloat16* CXb   = (__hip_bfloat16*)(ws + 234881024L);    // 32 MB x@Wc_top+bc
  __hip_bfloat16* Wru_t = (__hip_bfloat16*)(ws + 268435456L);    // 8 MB  (2048 x 2048)
  __hip_bfloat16* W1cx_t= (__hip_bfloat16*)(ws + 276824064L);    // 4 MB  (2048 x 1024)
  __hip_bfloat16* Wcb_t = (__hip_bfloat16*)(ws + 281018368L);    // 2 MB  (1024 x 1024)
  __hip_bfloat16* W2_t  = (__hip_bfloat16*)(ws + 283115520L);    // 2 MB  (1024 x 1024)
  __hip_bfloat16* Wg_t  = (__hip_bfloat16*)(ws + 285212672L);    // 4 MB  (1024 x 2048)
  __hip_bfloat16* CB    = NB;   // NB dead after G3; reuse for tanh(c)

  prep_k<<<12288, 256, 0, stream>>>((const float4*)inputs, (const float4*)state,
                                    A1, NB, Wr, Wu, W1, Wc, W2, Wg,
                                    Wru_t, W1cx_t, Wcb_t, W2_t, Wg_t);

  // G1: [x|state] @ [Wr|Wu] -> rs, u   (64 m x 8 n)
  gemm256<0><<<512, 512, 0, stream>>>(A1, 2048, Wru_t, 2048, 8,
                                      br, bu, A1, nullptr, nullptr, nullptr,
                                      RS, Ub, nullptr);
  // G2: x @ [W1|Wc_top] -> sem, cx
  gemm256<1><<<512, 512, 0, stream>>>(A1, 2048, W1cx_t, 1024, 8,
                                      b1, bc, nullptr, nullptr, nullptr, nullptr,
                                      SN, CXb, nullptr);
  // G3: neighbors @ W2 -> nei
  gemm256<2><<<256, 512, 0, stream>>>(NB, 1024, W2_t, 1024, 4,
                                      b2, nullptr, nullptr, nullptr, nullptr, nullptr,
                                      SN, nullptr, nullptr);
  // final_c: cb = tanh(cx + rs @ Wc_bot^T) -> CB
  gemm256<3><<<256, 512, 0, stream>>>(RS, 1024, Wcb_t, 1024, 4,
                                      nullptr, nullptr, nullptr, CXb, nullptr, nullptr,
                                      CB, nullptr, nullptr);
  // final_g: out = u*state + (1-u)*cb*sigmoid([sem|nei] @ Wg^T + bg)
  gemm256<4><<<256, 512, 0, stream>>>(SN, 2048, Wg_t, 2048, 4,
                                      bg, nullptr, A1, nullptr, CB, Ub,
                                      nullptr, nullptr, out);
}

// Round 9
// 515.559 us; speedup vs baseline: 1.1028x; 1.1028x over previous
//
#include <hip/hip_runtime.h>
#include <hip/hip_bf16.h>
#include <math.h>

#define Bsz 16384
#define HIDc 1024

typedef __attribute__((ext_vector_type(8))) short short8_t;
typedef __attribute__((ext_vector_type(4))) float f32x4;
typedef __attribute__((ext_vector_type(4))) short s16x4;

typedef __attribute__((address_space(1))) const unsigned char* gp1_t;
typedef __attribute__((address_space(3))) unsigned char* lp3_t;

__device__ __forceinline__ float sigf(float x) { return 1.0f / (1.0f + __expf(-x)); }
__device__ __forceinline__ float tanh_fast(float x) {
  x = fminf(fmaxf(x, -10.f), 10.f);
  float t = __expf(2.f * x);
  return (t - 1.f) / (t + 1.f);
}

// Bijective XCD-chunked swizzle (T1, m204 form). r2 evidence: final FETCH
// 573 MB -> 280 MB. Keep everywhere.
__device__ __forceinline__ int xcd_map(int bid, int nwg) {
  const int q = nwg >> 3, r = nwg & 7;
  const int xcd = bid & 7, idx = bid >> 3;
  return (xcd < r ? xcd * (q + 1) : r * (q + 1) + (xcd - r) * q) + idx;
}

// Stage a 128x64 bf16 tile (16 KB) into LDS with global_load_lds width=16.
// LDS dest linear; k-slot XOR swizzle applied on the GLOBAL source address
// (both-sides-or-neither, rule #21): phys slot p of row r holds logical p^(r&7).
__device__ __forceinline__ void stage64(const __hip_bfloat16* __restrict__ g, long ld,
                                        __hip_bfloat16* l, int wave, int lane) {
  const int rsub = lane >> 3;                    // row within 8-row chunk
  const int kx = ((lane & 7) ^ rsub) << 3;       // swizzled source col (elems)
#pragma unroll
  for (int i = 0; i < 4; ++i) {
    const int chunk = i * 4 + wave;              // 0..15, 8 rows each
    const int row = chunk * 8 + rsub;
    const __hip_bfloat16* gp = g + (long)row * ld + kx;
    __hip_bfloat16* lp = l + chunk * 512 + lane * 8;   // chunk*1024B + lane*16B
    __builtin_amdgcn_global_load_lds((gp1_t)gp, (lp3_t)lp, 16, 0, 0);
  }
}

// Serial m97-style K-loop (32 KB LDS). r2/r5-r8 evidence: every deeper
// pipeline variant (64KB dbuf, 3-buf vmcnt(6), 256^2 2-subphase, 256^2
// 4-quadrant) measured SLOWER than this 2-barrier serial schedule at
// 3-5 blocks/CU. Block-level TLP provides the overlap. Do not touch.
__device__ __forceinline__ void gemm_acc(const __hip_bfloat16* __restrict__ A, long lda,
                                         const __hip_bfloat16* __restrict__ Wt, long ldw,
                                         int K,
                                         __hip_bfloat16* lA, __hip_bfloat16* lB,
                                         f32x4 acc[4][4]) {
  const int tid = threadIdx.x;
  const int wave = tid >> 6, lane = tid & 63;
  const int wr = wave >> 1, wc = wave & 1;
  const int lm = lane & 15, hi = lane >> 4, l7 = lane & 7;
  for (int k0 = 0; k0 < K; k0 += 64) {
    __syncthreads();                       // previous compute done before overwrite
    stage64(A + k0, lda, lA, wave, lane);
    stage64(Wt + k0, ldw, lB, wave, lane);
    __syncthreads();                       // compiler drains vmcnt before barrier
#pragma unroll
    for (int ks = 0; ks < 2; ++ks) {
      short8_t a8[4], b8[4];
      const int sl = ks * 4 + hi;          // logical 16B slot 0..7
#pragma unroll
      for (int m = 0; m < 4; ++m) {
        const int r = wr * 64 + m * 16 + lm;
        a8[m] = *reinterpret_cast<const short8_t*>(lA + r * 64 + ((sl ^ l7) << 3));
      }
#pragma unroll
      for (int n = 0; n < 4; ++n) {
        const int r = wc * 64 + n * 16 + lm;
        b8[n] = *reinterpret_cast<const short8_t*>(lB + r * 64 + ((sl ^ l7) << 3));
      }
#pragma unroll
      for (int m = 0; m < 4; ++m)
#pragma unroll
        for (int n = 0; n < 4; ++n)
          acc[m][n] = __builtin_amdgcn_mfma_f32_16x16x32_bf16(a8[m], b8[n], acc[m][n], 0, 0, 0);
    }
  }
}

// EPI 0: G1 — col<1024: rs = sigmoid(v+br)*state_bf16 -> out0 (bf16, ld 1024)
//             col>=1024: u = sigmoid(v+bu)            -> out1 (bf16, ld 1024)
// EPI 1: G2 — col<1024: sem = relu(v+b1) -> out0 (bf16, ld 2048)
//             col>=1024: cx = v+bc       -> out1 (bf16, ld 1024)
// EPI 2: G3 — nei = relu(v+b2) -> out0 + 1024 (ld 2048)
// EPI 3: final_c — cb = tanh(v + auxbf) -> out0 (bf16, ld 1024)
template <int EPI>
__global__ void gemm_k(const __hip_bfloat16* __restrict__ A, long lda,
                       const __hip_bfloat16* __restrict__ Wt, long ldw, int K, int nbx,
                       const float* __restrict__ bias0, const float* __restrict__ bias1,
                       const __hip_bfloat16* __restrict__ stbf,   // A1 (state at col 1024+)
                       const __hip_bfloat16* __restrict__ auxbf,  // EPI3: CXb (ld 1024)
                       __hip_bfloat16* __restrict__ out0, __hip_bfloat16* __restrict__ out1) {
  __shared__ __hip_bfloat16 lA[128 * 64], lB[128 * 64];
  f32x4 acc[4][4];
#pragma unroll
  for (int m = 0; m < 4; ++m)
#pragma unroll
    for (int n = 0; n < 4; ++n) acc[m][n] = (f32x4){0.f, 0.f, 0.f, 0.f};

  const int wg = xcd_map(blockIdx.x, gridDim.x);
  const long mBase = (long)(wg / nbx) * 128;
  const long nBase = (long)(wg % nbx) * 128;
  gemm_acc(A + mBase * lda, lda, Wt + nBase * ldw, ldw, K, lA, lB, acc);

  const int tid = threadIdx.x, wave = tid >> 6, lane = tid & 63;
  const int wr = wave >> 1, wc = wave & 1, lm = lane & 15, hi = lane >> 4;
  const int row0 = (int)mBase + wr * 64 + hi * 4;
  const int col0 = (int)nBase + wc * 64 + lm;
#pragma unroll
  for (int m = 0; m < 4; ++m)
#pragma unroll
    for (int n = 0; n < 4; ++n)
#pragma unroll
      for (int j = 0; j < 4; ++j) {
        const long row = row0 + m * 16 + j;
        const int col = col0 + n * 16;
        const float v = acc[m][n][j];
        if (EPI == 0) {
          if (col < HIDc) {
            float rr = sigf(v + bias0[col]);
            float st = __bfloat162float(stbf[row * 2048 + 1024 + col]);
            out0[row * HIDc + col] = __float2bfloat16(rr * st);
          } else {
            int c = col - HIDc;
            out1[row * HIDc + c] = __float2bfloat16(sigf(v + bias1[c]));
          }
        } else if (EPI == 1) {
          if (col < HIDc) {
            out0[row * 2048 + col] = __float2bfloat16(fmaxf(v + bias0[col], 0.f));
          } else {
            int c = col - HIDc;
            out1[row * HIDc + c] = __float2bfloat16(v + bias1[c]);
          }
        } else if (EPI == 2) {
          out0[row * 2048 + HIDc + col] = __float2bfloat16(fmaxf(v + bias0[col], 0.f));
        } else {
          const long idx = row * HIDc + col;
          float cb = tanh_fast(v + __bfloat162float(auxbf[idx]));
          out0[idx] = __float2bfloat16(cb);
        }
      }
}

// final_g: accG = [sem|nei] @ Wg^T (K=2048);
// out = u*state + (1-u)*cb*sigmoid(accG+bg)   — acc-only live set, no spills.
__global__ void final_g(const __hip_bfloat16* __restrict__ SN,
                        const __hip_bfloat16* __restrict__ Wgt,
                        const __hip_bfloat16* __restrict__ CB,
                        const __hip_bfloat16* __restrict__ U,
                        const __hip_bfloat16* __restrict__ stbf,  // A1 (state at col 1024+)
                        const float* __restrict__ bg,
                        float* __restrict__ out, int nbx) {
  __shared__ __hip_bfloat16 lA[128 * 64], lB[128 * 64];
  f32x4 acc[4][4];
#pragma unroll
  for (int m = 0; m < 4; ++m)
#pragma unroll
    for (int n = 0; n < 4; ++n) acc[m][n] = (f32x4){0.f, 0.f, 0.f, 0.f};

  const int wg = xcd_map(blockIdx.x, gridDim.x);
  const long mBase = (long)(wg / nbx) * 128;
  const long nBase = (long)(wg % nbx) * 128;
  gemm_acc(SN + mBase * 2048, 2048, Wgt + nBase * 2048, 2048, 2048, lA, lB, acc);

  const int tid = threadIdx.x, wave = tid >> 6, lane = tid & 63;
  const int wr = wave >> 1, wc = wave & 1, lm = lane & 15, hi = lane >> 4;
  const int row0 = (int)mBase + wr * 64 + hi * 4;
  const int col0 = (int)nBase + wc * 64 + lm;
#pragma unroll
  for (int m = 0; m < 4; ++m)
#pragma unroll
    for (int n = 0; n < 4; ++n)
#pragma unroll
      for (int j = 0; j < 4; ++j) {
        const long row = row0 + m * 16 + j;
        const int col = col0 + n * 16;
        const long idx = row * HIDc + col;
        float g = sigf(acc[m][n][j] + bg[col]);
        float u = __bfloat162float(U[idx]);
        float cb = __bfloat162float(CB[idx]);
        float st = __bfloat162float(stbf[row * 2048 + 1024 + col]);
        out[idx] = u * st + (1.f - u) * cb * g;
      }
}

// One prep kernel (proven r7): blocks [0,10240) transpose all 7 weight views
// to (N,K) bf16; blocks [10240,12288) pack activations to bf16.
__global__ __launch_bounds__(256)
void prep_k(const float4* __restrict__ in4, const float4* __restrict__ st4,
            __hip_bfloat16* __restrict__ A1, __hip_bfloat16* __restrict__ NB,
            const float* __restrict__ Wr, const float* __restrict__ Wu,
            const float* __restrict__ W1, const float* __restrict__ Wc,
            const float* __restrict__ W2, const float* __restrict__ Wg,
            __hip_bfloat16* __restrict__ Wru_t, __hip_bfloat16* __restrict__ W1cx_t,
            __hip_bfloat16* __restrict__ Wcb_t, __hip_bfloat16* __restrict__ W2_t,
            __hip_bfloat16* __restrict__ Wg_t) {
  const int bid = blockIdx.x;
  if (bid < 10240) {
    const float* s_; __hip_bfloat16* d_; long ldo; int j, ktiles;
    if (bid < 2048)      { j = bid;        s_ = Wr; d_ = Wru_t;               ldo = 2048; ktiles = 64; }
    else if (bid < 4096) { j = bid - 2048; s_ = Wu; d_ = Wru_t + 1024L * 2048; ldo = 2048; ktiles = 64; }
    else if (bid < 5120) { j = bid - 4096; s_ = W1; d_ = W1cx_t;              ldo = 1024; ktiles = 32; }
    else if (bid < 6144) { j = bid - 5120; s_ = Wc; d_ = W1cx_t + 1024L * 1024; ldo = 1024; ktiles = 32; }
    else if (bid < 7168) { j = bid - 6144; s_ = Wc + 1024L * 1024; d_ = Wcb_t; ldo = 1024; ktiles = 32; }
    else if (bid < 8192) { j = bid - 7168; s_ = W2; d_ = W2_t;                ldo = 1024; ktiles = 32; }
    else                 { j = bid - 8192; s_ = Wg; d_ = Wg_t;                ldo = 2048; ktiles = 64; }
    const int k0 = (j % ktiles) * 32, n0 = (j / ktiles) * 32;
    __shared__ float t[32][33];
    const int tx = threadIdx.x & 31, ty = threadIdx.x >> 5;
#pragma unroll
    for (int dy = 0; dy < 32; dy += 8)
      t[ty + dy][tx] = s_[(long)(k0 + ty + dy) * 1024 + n0 + tx];
    __syncthreads();
#pragma unroll
    for (int dy = 0; dy < 32; dy += 8)
      d_[(long)(n0 + ty + dy) * ldo + k0 + tx] = __float2bfloat16(t[tx][ty + dy]);
  } else {
    const long NI4 = (long)Bsz * 2048 / 4;
    const long NS4 = (long)Bsz * 1024 / 4;
    for (long i = (long)(bid - 10240) * 256 + threadIdx.x; i < NI4 + NS4;
         i += 2048L * 256) {
      float4 v;
      __hip_bfloat16* dst;
      if (i < NI4) {
        v = in4[i];
        long e = i << 2;
        long row = e >> 11;
        int col = (int)(e & 2047);
        dst = (col < 1024) ? (A1 + row * 2048 + col) : (NB + row * 1024 + (col - 1024));
      } else {
        long jj = i - NI4;
        v = st4[jj];
        long e = jj << 2;
        long row = e >> 10;
        int col = (int)(e & 1023);
        dst = A1 + row * 2048 + 1024 + col;
      }
      union { __hip_bfloat16 h[4]; s16x4 s; } u;
      u.h[0] = __float2bfloat16(v.x);
      u.h[1] = __float2bfloat16(v.y);
      u.h[2] = __float2bfloat16(v.z);
      u.h[3] = __float2bfloat16(v.w);
      *reinterpret_cast<s16x4*>(dst) = u.s;
    }
  }
}

extern "C" void kernel_launch(void* const* d_in, const int* in_sizes, int n_in,
                              void* d_out, int out_size, void* d_ws, size_t ws_size,
                              hipStream_t stream) {
  const float* inputs = (const float*)d_in[0];
  const float* state = (const float*)d_in[1];
  const float* Wr = (const float*)d_in[2];
  const float* br = (const float*)d_in[3];
  const float* Wu = (const float*)d_in[4];
  const float* bu = (const float*)d_in[5];
  const float* Wc = (const float*)d_in[6];
  const float* bc = (const float*)d_in[7];
  const float* W1 = (const float*)d_in[8];
  const float* b1 = (const float*)d_in[9];
  const float* W2 = (const float*)d_in[10];
  const float* b2 = (const float*)d_in[11];
  const float* Wg = (const float*)d_in[12];
  const float* bg = (const float*)d_in[13];
  float* out = (float*)d_out;

  char* ws = (char*)d_ws;
  __hip_bfloat16* A1    = (__hip_bfloat16*)(ws);                 // 64 MB [x|state]
  __hip_bfloat16* NB    = (__hip_bfloat16*)(ws + 67108864L);     // 32 MB neighbors -> CB
  __hip_bfloat16* RS    = (__hip_bfloat16*)(ws + 100663296L);    // 32 MB r*state
  __hip_bfloat16* Ub    = (__hip_bfloat16*)(ws + 134217728L);    // 32 MB u
  __hip_bfloat16* SN    = (__hip_bfloat16*)(ws + 167772160L);    // 64 MB [sem|nei]
  __hip_bfloat16* CXb   = (__hip_bfloat16*)(ws + 234881024L);    // 32 MB x@Wc_top+bc
  __hip_bfloat16* Wru_t = (__hip_bfloat16*)(ws + 268435456L);    // 8 MB  (2048 x 2048)
  __hip_bfloat16* W1cx_t= (__hip_bfloat16*)(ws + 276824064L);    // 4 MB  (2048 x 1024)
  __hip_bfloat16* Wcb_t = (__hip_bfloat16*)(ws + 281018368L);    // 2 MB  (1024 x 1024)
  __hip_bfloat16* W2_t  = (__hip_bfloat16*)(ws + 283115520L);    // 2 MB  (1024 x 1024)
  __hip_bfloat16* Wg_t  = (__hip_bfloat16*)(ws + 285212672L);    // 4 MB  (1024 x 2048)
  __hip_bfloat16* CB    = NB;   // NB dead after G3; reuse for tanh(c)

  prep_k<<<12288, 256, 0, stream>>>((const float4*)inputs, (const float4*)state,
                                    A1, NB, Wr, Wu, W1, Wc, W2, Wg,
                                    Wru_t, W1cx_t, Wcb_t, W2_t, Wg_t);

  // G1: [x|state] @ [Wr|Wu] -> rs, u   (128 m x 16 n, 128^2 tiles)
  gemm_k<0><<<2048, 256, 0, stream>>>(A1, 2048, Wru_t, 2048, 2048, 16,
                                      br, bu, A1, nullptr, RS, Ub);
  // G2: x @ [W1|Wc_top] -> sem, cx
  gemm_k<1><<<2048, 256, 0, stream>>>(A1, 2048, W1cx_t, 1024, 1024, 16,
                                      b1, bc, nullptr, nullptr, SN, CXb);
  // G3: neighbors @ W2 -> nei
  gemm_k<2><<<1024, 256, 0, stream>>>(NB, 1024, W2_t, 1024, 1024, 8,
                                      b2, nullptr, nullptr, nullptr, SN, nullptr);
  // final_c: cb = tanh(cx + rs @ Wc_bot^T) -> CB
  gemm_k<3><<<1024, 256, 0, stream>>>(RS, 1024, Wcb_t, 1024, 1024, 8,
                                      nullptr, nullptr, nullptr, CXb, CB, nullptr);
  // final_g: out = u*state + (1-u)*cb*sigmoid([sem|nei] @ Wg^T + bg)
  final_g<<<1024, 256, 0, stream>>>(SN, Wg_t, CB, Ub, A1, bg, out, 8);
}

// Round 10
// 507.424 us; speedup vs baseline: 1.1205x; 1.0160x over previous
//
#include <hip/hip_runtime.h>
#include <hip/hip_bf16.h>
#include <math.h>

#define Bsz 16384
#define HIDc 1024

typedef __attribute__((ext_vector_type(8))) short short8_t;
typedef __attribute__((ext_vector_type(4))) float f32x4;
typedef __attribute__((ext_vector_type(4))) short s16x4;

typedef __attribute__((address_space(1))) const unsigned char* gp1_t;
typedef __attribute__((address_space(3))) unsigned char* lp3_t;

__device__ __forceinline__ float sigf(float x) { return 1.0f / (1.0f + __expf(-x)); }
__device__ __forceinline__ float tanh_fast(float x) {
  x = fminf(fmaxf(x, -10.f), 10.f);
  float t = __expf(2.f * x);
  return (t - 1.f) / (t + 1.f);
}

// Bijective XCD-chunked swizzle (T1, m204 form). r2 evidence: final FETCH
// 573 MB -> 280 MB. Keep everywhere.
__device__ __forceinline__ int xcd_map(int bid, int nwg) {
  const int q = nwg >> 3, r = nwg & 7;
  const int xcd = bid & 7, idx = bid >> 3;
  return (xcd < r ? xcd * (q + 1) : r * (q + 1) + (xcd - r) * q) + idx;
}

// Stage a 128x64 bf16 tile (16 KB) into LDS with global_load_lds width=16.
// LDS dest linear; k-slot XOR swizzle applied on the GLOBAL source address
// (both-sides-or-neither, rule #21): phys slot p of row r holds logical p^(r&7).
__device__ __forceinline__ void stage64(const __hip_bfloat16* __restrict__ g, long ld,
                                        __hip_bfloat16* l, int wave, int lane) {
  const int rsub = lane >> 3;                    // row within 8-row chunk
  const int kx = ((lane & 7) ^ rsub) << 3;       // swizzled source col (elems)
#pragma unroll
  for (int i = 0; i < 4; ++i) {
    const int chunk = i * 4 + wave;              // 0..15, 8 rows each
    const int row = chunk * 8 + rsub;
    const __hip_bfloat16* gp = g + (long)row * ld + kx;
    __hip_bfloat16* lp = l + chunk * 512 + lane * 8;   // chunk*1024B + lane*16B
    __builtin_amdgcn_global_load_lds((gp1_t)gp, (lp3_t)lp, 16, 0, 0);
  }
}

// Serial m97-style K-loop (32 KB LDS). r2/r5-r8 evidence: every deeper
// pipeline variant (64KB dbuf, 3-buf vmcnt(6), 256^2 2-subphase, 256^2
// 4-quadrant) measured SLOWER than this 2-barrier serial schedule at
// 3-5 blocks/CU. Block-level TLP provides the overlap. Do not touch.
__device__ __forceinline__ void gemm_acc(const __hip_bfloat16* __restrict__ A, long lda,
                                         const __hip_bfloat16* __restrict__ Wt, long ldw,
                                         int K,
                                         __hip_bfloat16* lA, __hip_bfloat16* lB,
                                         f32x4 acc[4][4]) {
  const int tid = threadIdx.x;
  const int wave = tid >> 6, lane = tid & 63;
  const int wr = wave >> 1, wc = wave & 1;
  const int lm = lane & 15, hi = lane >> 4, l7 = lane & 7;
  for (int k0 = 0; k0 < K; k0 += 64) {
    __syncthreads();                       // previous compute done before overwrite
    stage64(A + k0, lda, lA, wave, lane);
    stage64(Wt + k0, ldw, lB, wave, lane);
    __syncthreads();                       // compiler drains vmcnt before barrier
#pragma unroll
    for (int ks = 0; ks < 2; ++ks) {
      short8_t a8[4], b8[4];
      const int sl = ks * 4 + hi;          // logical 16B slot 0..7
#pragma unroll
      for (int m = 0; m < 4; ++m) {
        const int r = wr * 64 + m * 16 + lm;
        a8[m] = *reinterpret_cast<const short8_t*>(lA + r * 64 + ((sl ^ l7) << 3));
      }
#pragma unroll
      for (int n = 0; n < 4; ++n) {
        const int r = wc * 64 + n * 16 + lm;
        b8[n] = *reinterpret_cast<const short8_t*>(lB + r * 64 + ((sl ^ l7) << 3));
      }
#pragma unroll
      for (int m = 0; m < 4; ++m)
#pragma unroll
        for (int n = 0; n < 4; ++n)
          acc[m][n] = __builtin_amdgcn_mfma_f32_16x16x32_bf16(a8[m], b8[n], acc[m][n], 0, 0, 0);
    }
  }
}

// mega_k: G1+G2+G3 in one dispatch (independent GEMMs; removes 2 launch gaps
// and 2 ramp-down tails; long-K G1 segment first for load balance).
//   [0,2048):    G1  [x|state]@[Wr|Wu], K=2048 -> rs=sig(v+br)*st, u=sig(v+bu)
//   [2048,4096): G2  x@[W1|Wc_top],     K=1024 -> sem=relu(v+b1)->SN, cx=v+bc
//   [4096,5120): G3  neighbors@W2,      K=1024 -> nei=relu(v+b2)->SN+1024
__global__ void mega_k(const __hip_bfloat16* __restrict__ A1,
                       const __hip_bfloat16* __restrict__ NB,
                       const __hip_bfloat16* __restrict__ Wru,
                       const __hip_bfloat16* __restrict__ W1cx,
                       const __hip_bfloat16* __restrict__ W2t,
                       const float* __restrict__ br, const float* __restrict__ bu,
                       const float* __restrict__ b1, const float* __restrict__ bc,
                       const float* __restrict__ b2,
                       __hip_bfloat16* __restrict__ RS, __hip_bfloat16* __restrict__ Ub,
                       __hip_bfloat16* __restrict__ SN, __hip_bfloat16* __restrict__ CXb) {
  __shared__ __hip_bfloat16 lA[128 * 64], lB[128 * 64];
  const int bid = blockIdx.x;
  const __hip_bfloat16 *A, *Wt;
  long lda, ldw;
  int K, nbx, epi, local, seg;
  if (bid < 2048)      { local = bid;        seg = 2048; epi = 0; A = A1; lda = 2048; Wt = Wru;  ldw = 2048; K = 2048; nbx = 16; }
  else if (bid < 4096) { local = bid - 2048; seg = 2048; epi = 1; A = A1; lda = 2048; Wt = W1cx; ldw = 1024; K = 1024; nbx = 16; }
  else                 { local = bid - 4096; seg = 1024; epi = 2; A = NB; lda = 1024; Wt = W2t;  ldw = 1024; K = 1024; nbx = 8;  }
  // segment bases are multiples of 8, so local%8 == global bid%8 == XCD id
  const int wg = xcd_map(local, seg);
  const long mBase = (long)(wg / nbx) * 128;
  const long nBase = (long)(wg % nbx) * 128;

  f32x4 acc[4][4];
#pragma unroll
  for (int m = 0; m < 4; ++m)
#pragma unroll
    for (int n = 0; n < 4; ++n) acc[m][n] = (f32x4){0.f, 0.f, 0.f, 0.f};

  gemm_acc(A + mBase * lda, lda, Wt + nBase * ldw, ldw, K, lA, lB, acc);

  const int tid = threadIdx.x, wave = tid >> 6, lane = tid & 63;
  const int wr = wave >> 1, wc = wave & 1, lm = lane & 15, hi = lane >> 4;
  const int row0 = (int)mBase + wr * 64 + hi * 4;
  const int col0 = (int)nBase + wc * 64 + lm;
#pragma unroll
  for (int m = 0; m < 4; ++m)
#pragma unroll
    for (int n = 0; n < 4; ++n)
#pragma unroll
      for (int j = 0; j < 4; ++j) {
        const long row = row0 + m * 16 + j;
        const int col = col0 + n * 16;
        const float v = acc[m][n][j];
        if (epi == 0) {
          if (col < HIDc) {
            float rr = sigf(v + br[col]);
            float st = __bfloat162float(A1[row * 2048 + 1024 + col]);
            RS[row * HIDc + col] = __float2bfloat16(rr * st);
          } else {
            int c = col - HIDc;
            Ub[row * HIDc + c] = __float2bfloat16(sigf(v + bu[c]));
          }
        } else if (epi == 1) {
          if (col < HIDc) {
            SN[row * 2048 + col] = __float2bfloat16(fmaxf(v + b1[col], 0.f));
          } else {
            int c = col - HIDc;
            CXb[row * HIDc + c] = __float2bfloat16(v + bc[c]);
          }
        } else {
          SN[row * 2048 + HIDc + col] = __float2bfloat16(fmaxf(v + b2[col], 0.f));
        }
      }
}

// final_c: cb = tanh(cx + rs @ Wc_bot^T) -> CB (bf16). Unchanged from r9.
__global__ void final_c(const __hip_bfloat16* __restrict__ A, long lda,
                        const __hip_bfloat16* __restrict__ Wt, long ldw, int K, int nbx,
                        const __hip_bfloat16* __restrict__ auxbf,  // CXb (ld 1024)
                        __hip_bfloat16* __restrict__ out0) {
  __shared__ __hip_bfloat16 lA[128 * 64], lB[128 * 64];
  f32x4 acc[4][4];
#pragma unroll
  for (int m = 0; m < 4; ++m)
#pragma unroll
    for (int n = 0; n < 4; ++n) acc[m][n] = (f32x4){0.f, 0.f, 0.f, 0.f};

  const int wg = xcd_map(blockIdx.x, gridDim.x);
  const long mBase = (long)(wg / nbx) * 128;
  const long nBase = (long)(wg % nbx) * 128;
  gemm_acc(A + mBase * lda, lda, Wt + nBase * ldw, ldw, K, lA, lB, acc);

  const int tid = threadIdx.x, wave = tid >> 6, lane = tid & 63;
  const int wr = wave >> 1, wc = wave & 1, lm = lane & 15, hi = lane >> 4;
  const int row0 = (int)mBase + wr * 64 + hi * 4;
  const int col0 = (int)nBase + wc * 64 + lm;
#pragma unroll
  for (int m = 0; m < 4; ++m)
#pragma unroll
    for (int n = 0; n < 4; ++n)
#pragma unroll
      for (int j = 0; j < 4; ++j) {
        const long row = row0 + m * 16 + j;
        const int col = col0 + n * 16;
        const long idx = row * HIDc + col;
        float cb = tanh_fast(acc[m][n][j] + __bfloat162float(auxbf[idx]));
        out0[idx] = __float2bfloat16(cb);
      }
}

// final_g: accG = [sem|nei] @ Wg^T (K=2048);
// out = u*state + (1-u)*cb*sigmoid(accG+bg). Unchanged from r9.
__global__ void final_g(const __hip_bfloat16* __restrict__ SN,
                        const __hip_bfloat16* __restrict__ Wgt,
                        const __hip_bfloat16* __restrict__ CB,
                        const __hip_bfloat16* __restrict__ U,
                        const __hip_bfloat16* __restrict__ stbf,  // A1 (state at col 1024+)
                        const float* __restrict__ bg,
                        float* __restrict__ out, int nbx) {
  __shared__ __hip_bfloat16 lA[128 * 64], lB[128 * 64];
  f32x4 acc[4][4];
#pragma unroll
  for (int m = 0; m < 4; ++m)
#pragma unroll
    for (int n = 0; n < 4; ++n) acc[m][n] = (f32x4){0.f, 0.f, 0.f, 0.f};

  const int wg = xcd_map(blockIdx.x, gridDim.x);
  const long mBase = (long)(wg / nbx) * 128;
  const long nBase = (long)(wg % nbx) * 128;
  gemm_acc(SN + mBase * 2048, 2048, Wgt + nBase * 2048, 2048, 2048, lA, lB, acc);

  const int tid = threadIdx.x, wave = tid >> 6, lane = tid & 63;
  const int wr = wave >> 1, wc = wave & 1, lm = lane & 15, hi = lane >> 4;
  const int row0 = (int)mBase + wr * 64 + hi * 4;
  const int col0 = (int)nBase + wc * 64 + lm;
#pragma unroll
  for (int m = 0; m < 4; ++m)
#pragma unroll
    for (int n = 0; n < 4; ++n)
#pragma unroll
      for (int j = 0; j < 4; ++j) {
        const long row = row0 + m * 16 + j;
        const int col = col0 + n * 16;
        const long idx = row * HIDc + col;
        float g = sigf(acc[m][n][j] + bg[col]);
        float u = __bfloat162float(U[idx]);
        float cb = __bfloat162float(CB[idx]);
        float st = __bfloat162float(stbf[row * 2048 + 1024 + col]);
        out[idx] = u * st + (1.f - u) * cb * g;
      }
}

// One prep kernel (proven r7): blocks [0,10240) transpose all 7 weight views
// to (N,K) bf16; blocks [10240,12288) pack activations to bf16.
__global__ __launch_bounds__(256)
void prep_k(const float4* __restrict__ in4, const float4* __restrict__ st4,
            __hip_bfloat16* __restrict__ A1, __hip_bfloat16* __restrict__ NB,
            const float* __restrict__ Wr, const float* __restrict__ Wu,
            const float* __restrict__ W1, const float* __restrict__ Wc,
            const float* __restrict__ W2, const float* __restrict__ Wg,
            __hip_bfloat16* __restrict__ Wru_t, __hip_bfloat16* __restrict__ W1cx_t,
            __hip_bfloat16* __restrict__ Wcb_t, __hip_bfloat16* __restrict__ W2_t,
            __hip_bfloat16* __restrict__ Wg_t) {
  const int bid = blockIdx.x;
  if (bid < 10240) {
    const float* s_; __hip_bfloat16* d_; long ldo; int j, ktiles;
    if (bid < 2048)      { j = bid;        s_ = Wr; d_ = Wru_t;               ldo = 2048; ktiles = 64; }
    else if (bid < 4096) { j = bid - 2048; s_ = Wu; d_ = Wru_t + 1024L * 2048; ldo = 2048; ktiles = 64; }
    else if (bid < 5120) { j = bid - 4096; s_ = W1; d_ = W1cx_t;              ldo = 1024; ktiles = 32; }
    else if (bid < 6144) { j = bid - 5120; s_ = Wc; d_ = W1cx_t + 1024L * 1024; ldo = 1024; ktiles = 32; }
    else if (bid < 7168) { j = bid - 6144; s_ = Wc + 1024L * 1024; d_ = Wcb_t; ldo = 1024; ktiles = 32; }
    else if (bid < 8192) { j = bid - 7168; s_ = W2; d_ = W2_t;                ldo = 1024; ktiles = 32; }
    else                 { j = bid - 8192; s_ = Wg; d_ = Wg_t;                ldo = 2048; ktiles = 64; }
    const int k0 = (j % ktiles) * 32, n0 = (j / ktiles) * 32;
    __shared__ float t[32][33];
    const int tx = threadIdx.x & 31, ty = threadIdx.x >> 5;
#pragma unroll
    for (int dy = 0; dy < 32; dy += 8)
      t[ty + dy][tx] = s_[(long)(k0 + ty + dy) * 1024 + n0 + tx];
    __syncthreads();
#pragma unroll
    for (int dy = 0; dy < 32; dy += 8)
      d_[(long)(n0 + ty + dy) * ldo + k0 + tx] = __float2bfloat16(t[tx][ty + dy]);
  } else {
    const long NI4 = (long)Bsz * 2048 / 4;
    const long NS4 = (long)Bsz * 1024 / 4;
    for (long i = (long)(bid - 10240) * 256 + threadIdx.x; i < NI4 + NS4;
         i += 2048L * 256) {
      float4 v;
      __hip_bfloat16* dst;
      if (i < NI4) {
        v = in4[i];
        long e = i << 2;
        long row = e >> 11;
        int col = (int)(e & 2047);
        dst = (col < 1024) ? (A1 + row * 2048 + col) : (NB + row * 1024 + (col - 1024));
      } else {
        long jj = i - NI4;
        v = st4[jj];
        long e = jj << 2;
        long row = e >> 10;
        int col = (int)(e & 1023);
        dst = A1 + row * 2048 + 1024 + col;
      }
      union { __hip_bfloat16 h[4]; s16x4 s; } u;
      u.h[0] = __float2bfloat16(v.x);
      u.h[1] = __float2bfloat16(v.y);
      u.h[2] = __float2bfloat16(v.z);
      u.h[3] = __float2bfloat16(v.w);
      *reinterpret_cast<s16x4*>(dst) = u.s;
    }
  }
}

extern "C" void kernel_launch(void* const* d_in, const int* in_sizes, int n_in,
                              void* d_out, int out_size, void* d_ws, size_t ws_size,
                              hipStream_t stream) {
  const float* inputs = (const float*)d_in[0];
  const float* state = (const float*)d_in[1];
  const float* Wr = (const float*)d_in[2];
  const float* br = (const float*)d_in[3];
  const float* Wu = (const float*)d_in[4];
  const float* bu = (const float*)d_in[5];
  const float* Wc = (const float*)d_in[6];
  const float* bc = (const float*)d_in[7];
  const float* W1 = (const float*)d_in[8];
  const float* b1 = (const float*)d_in[9];
  const float* W2 = (const float*)d_in[10];
  const float* b2 = (const float*)d_in[11];
  const float* Wg = (const float*)d_in[12];
  const float* bg = (const float*)d_in[13];
  float* out = (float*)d_out;

  char* ws = (char*)d_ws;
  __hip_bfloat16* A1    = (__hip_bfloat16*)(ws);                 // 64 MB [x|state]
  __hip_bfloat16* NB    = (__hip_bfloat16*)(ws + 67108864L);     // 32 MB neighbors -> CB
  __hip_bfloat16* RS    = (__hip_bfloat16*)(ws + 100663296L);    // 32 MB r*state
  __hip_bfloat16* Ub    = (__hip_bfloat16*)(ws + 134217728L);    // 32 MB u
  __hip_bfloat16* SN    = (__hip_bfloat16*)(ws + 167772160L);    // 64 MB [sem|nei]
  __hip_bfloat16* CXb   = (__hip_bfloat16*)(ws + 234881024L);    // 32 MB x@Wc_top+bc
  __hip_bfloat16* Wru_t = (__hip_bfloat16*)(ws + 268435456L);    // 8 MB  (2048 x 2048)
  __hip_bfloat16* W1cx_t= (__hip_bfloat16*)(ws + 276824064L);    // 4 MB  (2048 x 1024)
  __hip_bfloat16* Wcb_t = (__hip_bfloat16*)(ws + 281018368L);    // 2 MB  (1024 x 1024)
  __hip_bfloat16* W2_t  = (__hip_bfloat16*)(ws + 283115520L);    // 2 MB  (1024 x 1024)
  __hip_bfloat16* Wg_t  = (__hip_bfloat16*)(ws + 285212672L);    // 4 MB  (1024 x 2048)
  __hip_bfloat16* CB    = NB;   // NB dead after mega (G3 segment); reuse for tanh(c)

  prep_k<<<12288, 256, 0, stream>>>((const float4*)inputs, (const float4*)state,
                                    A1, NB, Wr, Wu, W1, Wc, W2, Wg,
                                    Wru_t, W1cx_t, Wcb_t, W2_t, Wg_t);

  // G1 + G2 + G3 fused into one dispatch (5120 blocks).
  mega_k<<<5120, 256, 0, stream>>>(A1, NB, Wru_t, W1cx_t, W2_t,
                                   br, bu, b1, bc, b2,
                                   RS, Ub, SN, CXb);

  // final_c: cb = tanh(cx + rs @ Wc_bot^T) -> CB
  final_c<<<1024, 256, 0, stream>>>(RS, 1024, Wcb_t, 1024, 1024, 8, CXb, CB);

  // final_g: out = u*state + (1-u)*cb*sigmoid([sem|nei] @ Wg^T + bg)
  final_g<<<1024, 256, 0, stream>>>(SN, Wg_t, CB, Ub, A1, bg, out, 8);
}